// Round 1
// baseline (1197.650 us; speedup 1.0000x reference)
//
#include <hip/hip_runtime.h>
#include <hip/hip_bf16.h>
#include <cstdint>

// Problem constants
#define BATCH 512
#define PL 200      // ctx rows
#define QL 60       // qry rows
#define QE 260      // encodings rows per batch
#define DD 512      // feature dim
// out: [512][200][2048] fp32 ; per-batch slab = 409600 floats = 1,638,400 B

typedef __attribute__((ext_vector_type(8))) short s8v;   // 8 bf16 bit-patterns
typedef __attribute__((ext_vector_type(4))) float f4v;

__device__ __forceinline__ unsigned short f2bf(float x){
    unsigned int u = __float_as_uint(x);
    u = (u + 0x7FFFu + ((u >> 16) & 1u)) >> 16;   // RNE
    return (unsigned short)u;
}
__device__ __forceinline__ float bf2f(unsigned short h){
    return __uint_as_float(((unsigned int)h) << 16);
}
__device__ __forceinline__ float4 mul4(float4 a, float4 b){
    return make_float4(a.x*b.x, a.y*b.y, a.z*b.z, a.w*b.w);
}
__device__ __forceinline__ float4 scale4(float s, float4 v){
    return make_float4(s*v.x, s*v.y, s*v.z, s*v.w);
}

// ---------------- Kernel 1: sim (MFMA bf16-split) + softmax -> stash w (bf16) & w2 (fp32)
// LDS map (bytes):
//   qh ushort[64*520] @0       (66560)   qry hi, row stride 520 (16B-aligned rows, 2-way banks)
//   ql ushort[64*520] @66560   (66560)   qry lo
//   ch ushort[208*32] @133120  (13312)   ctx-chunk hi (BK=32, no pad: b128 reads hit 128B/cyc floor)
//   cl ushort[208*32] @146432  (13312)
//   msim float[208]   @159744  (832)
//   red  float[16]    @160576  (64)
#define K1_LDS 160640

__global__ __launch_bounds__(512) void k1_sim(const float* __restrict__ enc,
                                              float* __restrict__ out){
    extern __shared__ char lds[];
    unsigned short* qh = (unsigned short*)lds;
    unsigned short* ql = (unsigned short*)(lds + 66560);
    unsigned short* ch = (unsigned short*)(lds + 133120);
    unsigned short* cl = (unsigned short*)(lds + 146432);
    float* msim = (float*)(lds + 159744);
    float* red  = (float*)(lds + 160576);

    const int b   = blockIdx.x;
    const int tid = threadIdx.x;
    const int lane = tid & 63, wid = tid >> 6;
    const int col  = lane & 15, quad = lane >> 4;
    const float* cb = enc + (size_t)b * (QE*DD);   // ctx rows 0..199
    const float* qb = cb + PL*DD;                  // qry rows 0..59

    // stage qry -> bf16 hi/lo in LDS
    for (int idx = tid; idx < QL*256; idx += 512){          // 60 rows * 256 float2
        int row = idx >> 8, c2 = idx & 255;
        float2 g = *(const float2*)(qb + row*DD + c2*2);
        unsigned short h0 = f2bf(g.x), h1 = f2bf(g.y);
        unsigned short l0 = f2bf(g.x - bf2f(h0)), l1 = f2bf(g.y - bf2f(h1));
        *(unsigned int*)&qh[row*520 + c2*2] = (unsigned)h0 | ((unsigned)h1 << 16);
        *(unsigned int*)&ql[row*520 + c2*2] = (unsigned)l0 | ((unsigned)l1 << 16);
    }
    // zero qry pad rows 60..63 (full 520-col rows)
    for (int idx = tid; idx < 4*260; idx += 512){
        int row = 60 + idx/260, c = idx%260;
        *(unsigned int*)&qh[row*520 + c*2] = 0u;
        *(unsigned int*)&ql[row*520 + c*2] = 0u;
    }
    // zero ctx-chunk pad rows 200..207 (staging loop never touches them)
    for (int idx = tid; idx < 8*16; idx += 512){
        int row = 200 + idx/16, c = idx%16;
        *(unsigned int*)&ch[row*32 + c*2] = 0u;
        *(unsigned int*)&cl[row*32 + c*2] = 0u;
    }

    // p-tiles: 13 tiles of 16 rows over 8 waves
    int nt[2]; int ntc = 0;
    for (int t = wid; t < 13; t += 8) nt[ntc++] = t;
    f4v acc[2][4];
    #pragma unroll
    for (int i = 0; i < 2; ++i)
        #pragma unroll
        for (int t = 0; t < 4; ++t)
            acc[i][t] = (f4v){0.f,0.f,0.f,0.f};

    for (int ks = 0; ks < 16; ++ks){
        __syncthreads();
        // stage ctx rows 0..199, cols ks*32..+31 as bf16 hi/lo
        for (int idx = tid; idx < PL*16; idx += 512){       // 200 rows * 16 float2
            int row = idx >> 4, c2 = idx & 15;
            float2 g = *(const float2*)(cb + row*DD + ks*32 + c2*2);
            unsigned short h0 = f2bf(g.x), h1 = f2bf(g.y);
            unsigned short l0 = f2bf(g.x - bf2f(h0)), l1 = f2bf(g.y - bf2f(h1));
            *(unsigned int*)&ch[row*32 + c2*2] = (unsigned)h0 | ((unsigned)h1 << 16);
            *(unsigned int*)&cl[row*32 + c2*2] = (unsigned)l0 | ((unsigned)l1 << 16);
        }
        __syncthreads();

        const int kb = ks*32 + quad*8;
        s8v bh[4], bl[4];
        #pragma unroll
        for (int t = 0; t < 4; ++t){
            bh[t] = *(const s8v*)&qh[(t*16 + col)*520 + kb];
            bl[t] = *(const s8v*)&ql[(t*16 + col)*520 + kb];
        }
        #pragma unroll
        for (int i = 0; i < 2; ++i){
            if (i < ntc){
                const int p0 = nt[i]*16;
                s8v ah = *(const s8v*)&ch[(p0 + col)*32 + quad*8];
                s8v al = *(const s8v*)&cl[(p0 + col)*32 + quad*8];
                #pragma unroll
                for (int t = 0; t < 4; ++t){
                    acc[i][t] = __builtin_amdgcn_mfma_f32_16x16x32_bf16(ah, bh[t], acc[i][t], 0,0,0);
                    acc[i][t] = __builtin_amdgcn_mfma_f32_16x16x32_bf16(ah, bl[t], acc[i][t], 0,0,0);
                    acc[i][t] = __builtin_amdgcn_mfma_f32_16x16x32_bf16(al, bh[t], acc[i][t], 0,0,0);
                }
            }
        }
    }

    // per-row softmax over q (in-register, quad = 16 lanes hold one row across 4 tiles)
    unsigned short* wst = (unsigned short*)((char*)out + (size_t)b*1638400);
    float* w2st = (float*)((char*)out + (size_t)b*1638400 + 24000);
    #pragma unroll
    for (int i = 0; i < 2; ++i){
        if (i < ntc){
            const int p0 = nt[i]*16;
            #pragma unroll
            for (int r = 0; r < 4; ++r){
                const int p = p0 + quad*4 + r;
                float v0 = acc[i][0][r], v1 = acc[i][1][r], v2 = acc[i][2][r], v3 = acc[i][3][r];
                const bool v3ok = (48 + col) < QL;          // q = 48+col valid?
                float mv = fmaxf(fmaxf(v0, v1), v3ok ? fmaxf(v2, v3) : v2);
                #pragma unroll
                for (int off = 1; off < 16; off <<= 1) mv = fmaxf(mv, __shfl_xor(mv, off));
                float e0 = __expf(v0 - mv), e1 = __expf(v1 - mv), e2 = __expf(v2 - mv);
                float e3 = v3ok ? __expf(v3 - mv) : 0.f;
                float s = e0 + e1 + e2 + e3;
                #pragma unroll
                for (int off = 1; off < 16; off <<= 1) s += __shfl_xor(s, off);
                float inv = 1.f / s;
                if (p < PL){
                    if (col == 0) msim[p] = mv;
                    wst[p*60 + col]      = f2bf(e0*inv);
                    wst[p*60 + 16 + col] = f2bf(e1*inv);
                    wst[p*60 + 32 + col] = f2bf(e2*inv);
                    if (v3ok) wst[p*60 + 48 + col] = f2bf(e3*inv);
                }
            }
        }
    }
    __syncthreads();

    // w2 = softmax over p of max_sim
    float vv = (tid < PL) ? msim[tid] : -3.0e38f;
    float mv = vv;
    #pragma unroll
    for (int off = 1; off < 64; off <<= 1) mv = fmaxf(mv, __shfl_xor(mv, off));
    if (lane == 0) red[wid] = mv;
    __syncthreads();
    if (tid == 0){ float m = red[0]; for (int i = 1; i < 8; ++i) m = fmaxf(m, red[i]); red[8] = m; }
    __syncthreads();
    const float M = red[8];
    float e = (tid < PL) ? __expf(msim[tid] - M) : 0.f;
    float sv = e;
    #pragma unroll
    for (int off = 1; off < 64; off <<= 1) sv += __shfl_xor(sv, off);
    __syncthreads();              // everyone has read red[8]
    if (lane == 0) red[wid] = sv;
    __syncthreads();
    if (tid == 0){ float s = red[0]; for (int i = 1; i < 8; ++i) s += red[i]; red[9] = s; }
    __syncthreads();
    if (tid < PL) w2st[tid] = e / red[9];
}

// ---------------- Kernel 2: q2c GEMV + c2q (fp32 VALU) + fused epilogue
// LDS: qryl f32[60*512]@0 (122880) | wbl u16[200*60]@122880 (24000) | w2l f32[200]@146880 (800)
//      q2cp f32[1024]@147680 (4096) | q2cl f32[512]@151776 (2048)  => 153824 B
#define K2_LDS 153824

__global__ __launch_bounds__(1024) void k2_out(const float* __restrict__ enc,
                                               float* __restrict__ out){
    extern __shared__ char lds[];
    float* qryl = (float*)lds;
    unsigned short* wbl = (unsigned short*)(lds + 122880);
    float* w2l  = (float*)(lds + 146880);
    float* q2cp = (float*)(lds + 147680);
    float* q2cl = (float*)(lds + 151776);

    const int b   = blockIdx.x;
    const int tid = threadIdx.x;
    const float* cb = enc + (size_t)b*(QE*DD);
    const float* qb = cb + PL*DD;
    float* ob = out + (size_t)b*409600;
    const char* stash = (const char*)out + (size_t)b*1638400;

    // phase 0: pull stash (lives in rows p<4 of our own out slab) + qry into LDS
    for (int idx = tid; idx < 6000; idx += 1024)
        ((unsigned int*)wbl)[idx] = ((const unsigned int*)stash)[idx];
    for (int idx = tid; idx < PL; idx += 1024)
        w2l[idx] = ((const float*)(stash + 24000))[idx];
    for (int idx = tid; idx < QL*128; idx += 1024){          // 60*512/4 float4
        int row = idx >> 7, c4 = idx & 127;
        *(float4*)&qryl[row*512 + c4*4] = *(const float4*)(qb + row*DD + c4*4);
    }
    __syncthreads();

    // phase A: q2c_vec[d] = sum_p w2[p]*ctx[p][d]  (two p-halves)
    {
        const int d = tid & 511, h = tid >> 9;
        float a = 0.f;
        const float* cp = cb + (h*100)*DD + d;
        const float* wp = w2l + h*100;
        #pragma unroll 10
        for (int p = 0; p < 100; ++p) a += wp[p] * cp[p*DD];
        q2cp[(h << 9) + d] = a;
    }
    __syncthreads();
    if (tid < 512) q2cl[tid] = q2cp[tid] + q2cp[512 + tid];
    __syncthreads();

    // phase C: per-wave 4-row tiles; lane covers d in {4*lane, 256+4*lane}
    const int lane = tid & 63, wid = tid >> 6;
    const float4 qv0 = *(const float4*)&q2cl[lane*4];
    const float4 qv1 = *(const float4*)&q2cl[256 + lane*4];
    for (int t = wid; t < 50; t += 16){
        const int p0 = t*4;
        float4 a0[4], a1[4];
        #pragma unroll
        for (int r = 0; r < 4; ++r){
            a0[r] = make_float4(0.f,0.f,0.f,0.f);
            a1[r] = make_float4(0.f,0.f,0.f,0.f);
        }
        for (int q = 0; q < QL; ++q){
            float4 r0 = *(const float4*)&qryl[q*512 + lane*4];
            float4 r1 = *(const float4*)&qryl[q*512 + 256 + lane*4];
            #pragma unroll
            for (int r = 0; r < 4; ++r){
                float wv = bf2f(wbl[(p0 + r)*60 + q]);
                a0[r].x += wv*r0.x; a0[r].y += wv*r0.y; a0[r].z += wv*r0.z; a0[r].w += wv*r0.w;
                a1[r].x += wv*r1.x; a1[r].y += wv*r1.y; a1[r].z += wv*r1.z; a1[r].w += wv*r1.w;
            }
        }
        #pragma unroll
        for (int r = 0; r < 4; ++r){
            const int p = p0 + r;
            const float* cr = cb + p*DD;
            float4 c0 = *(const float4*)&cr[lane*4];
            float4 c1 = *(const float4*)&cr[256 + lane*4];
            float* orow = ob + p*2048;
            *(float4*)&orow[lane*4]          = c0;
            *(float4*)&orow[256  + lane*4]   = c1;
            *(float4*)&orow[512  + lane*4]   = a0[r];
            *(float4*)&orow[768  + lane*4]   = a1[r];
            *(float4*)&orow[1024 + lane*4]   = mul4(c0, a0[r]);
            *(float4*)&orow[1280 + lane*4]   = mul4(c1, a1[r]);
            *(float4*)&orow[1536 + lane*4]   = mul4(c0, qv0);
            *(float4*)&orow[1792 + lane*4]   = mul4(c1, qv1);
        }
    }
}

extern "C" void kernel_launch(void* const* d_in, const int* in_sizes, int n_in,
                              void* d_out, int out_size, void* d_ws, size_t ws_size,
                              hipStream_t stream){
    (void)in_sizes; (void)n_in; (void)d_ws; (void)ws_size; (void)out_size;
    const float* enc = (const float*)d_in[0];
    float* out = (float*)d_out;
    hipFuncSetAttribute((const void*)k1_sim, hipFuncAttributeMaxDynamicSharedMemorySize, K1_LDS);
    hipFuncSetAttribute((const void*)k2_out, hipFuncAttributeMaxDynamicSharedMemorySize, K2_LDS);
    hipLaunchKernelGGL(k1_sim, dim3(BATCH), dim3(512),  K1_LDS, stream, enc, out);
    hipLaunchKernelGGL(k2_out, dim3(BATCH), dim3(1024), K2_LDS, stream, enc, out);
}